// Round 4
// baseline (1077.159 us; speedup 1.0000x reference)
//
#include <hip/hip_runtime.h>
#include <hip/hip_bf16.h>
#include <hip/hip_fp16.h>

#define F_IN 128
#define F_E  32
#define DH   128   // D*H
#define HD   32    // D

__device__ __forceinline__ unsigned short f2bf(float f) {
    unsigned int x = __float_as_uint(f);
    unsigned int r = (x + 0x7fffu + ((x >> 16) & 1u)) >> 16;   // RNE
    return (unsigned short)r;
}

// ---- prep: We_fold[f][h] = sum_d W_edge[f][h*32+d] * attn[h][64+d]  (32x4)
__global__ void prep_kernel(const float* __restrict__ W_edge,
                            const float* __restrict__ attn,
                            float* __restrict__ wefold) {
    int t = threadIdx.x;            // 128 threads
    int f = t >> 2, h = t & 3;
    float s = 0.f;
#pragma unroll
    for (int d = 0; d < 32; ++d)
        s += W_edge[f * DH + h * HD + d] * attn[h * 96 + 64 + d];
    wefold[f * 4 + h] = s;
}

// ---- node projection GEMM (128x128 tile, 8x8 micro-tile) + per-head src scores
// s_dst is dropped: softmax ratio is invariant to the per-dst factor exp(s_dst).
__global__ __launch_bounds__(256, 4)
void node_proj_kernel(const float* __restrict__ x, const float* __restrict__ Wn,
                      const float* __restrict__ attn,
                      unsigned short* __restrict__ proj_bf,
                      float* __restrict__ s_src, int N) {
    __shared__ float xsT[32 * 132];
    __shared__ float ws[32 * 132];
    const int t  = threadIdx.x;
    const int n0 = blockIdx.x * 128;
    const int tc = t & 15, tn = t >> 4;
    const float4* x4  = (const float4*)x;
    const float4* Wn4 = (const float4*)Wn;

    float acc[2][2][4][4];
#pragma unroll
    for (int a = 0; a < 2; ++a)
#pragma unroll
        for (int b = 0; b < 2; ++b)
#pragma unroll
            for (int i = 0; i < 4; ++i)
#pragma unroll
                for (int j = 0; j < 4; ++j) acc[a][b][i][j] = 0.f;

    for (int ch = 0; ch < 4; ++ch) {
        __syncthreads();
        // stage x chunk transposed: xsT[kk][n]
#pragma unroll
        for (int j = 0; j < 4; ++j) {
            int idx = t + j * 256;          // 0..1023
            int n  = idx >> 3;              // 0..127
            int kq = idx & 7;               // 0..7 (float4 group)
            float4 v = make_float4(0.f, 0.f, 0.f, 0.f);
            if (n0 + n < N) v = x4[(size_t)(n0 + n) * 32 + ch * 8 + kq];
            int kk = kq * 4;
            xsT[(kk + 0) * 132 + n] = v.x;
            xsT[(kk + 1) * 132 + n] = v.y;
            xsT[(kk + 2) * 132 + n] = v.z;
            xsT[(kk + 3) * 132 + n] = v.w;
        }
        // stage W chunk row-major: ws[kk][c]
#pragma unroll
        for (int j = 0; j < 4; ++j) {
            int idx = t + j * 256;
            int kk = idx >> 5, cq = idx & 31;
            float4 v = Wn4[(size_t)(ch * 32 + kk) * 32 + cq];
            *(float4*)&ws[kk * 132 + cq * 4] = v;
        }
        __syncthreads();
#pragma unroll 4
        for (int kk = 0; kk < 32; ++kk) {
            float4 a0 = *(const float4*)&xsT[kk * 132 + tn * 4];
            float4 a1 = *(const float4*)&xsT[kk * 132 + 64 + tn * 4];
            float4 b0 = *(const float4*)&ws[kk * 132 + tc * 4];
            float4 b1 = *(const float4*)&ws[kk * 132 + 64 + tc * 4];
            float av[2][4] = {{a0.x, a0.y, a0.z, a0.w}, {a1.x, a1.y, a1.z, a1.w}};
            float bv[2][4] = {{b0.x, b0.y, b0.z, b0.w}, {b1.x, b1.y, b1.z, b1.w}};
#pragma unroll
            for (int ni = 0; ni < 2; ++ni)
#pragma unroll
                for (int ci = 0; ci < 2; ++ci)
#pragma unroll
                    for (int ii = 0; ii < 4; ++ii)
#pragma unroll
                        for (int jj = 0; jj < 4; ++jj)
                            acc[ni][ci][ii][jj] =
                                fmaf(av[ni][ii], bv[ci][jj], acc[ni][ci][ii][jj]);
        }
    }

    // epilogue: attention (src) vectors for this thread's 8 cols
    float asv[2][4];
#pragma unroll
    for (int ci = 0; ci < 2; ++ci)
#pragma unroll
        for (int jj = 0; jj < 4; ++jj) {
            int c = ci * 64 + tc * 4 + jj;
            int h = c >> 5, d = c & 31;
            asv[ci][jj] = attn[h * 96 + d];
        }

#pragma unroll
    for (int ni = 0; ni < 2; ++ni)
#pragma unroll
        for (int ii = 0; ii < 4; ++ii) {
            int n = n0 + ni * 64 + tn * 4 + ii;
            bool ok = (n < N);
            if (ok) {
                union { unsigned short h[4]; uint2 u; } p0, p1;
#pragma unroll
                for (int jj = 0; jj < 4; ++jj) {
                    p0.h[jj] = f2bf(acc[ni][0][ii][jj]);
                    p1.h[jj] = f2bf(acc[ni][1][ii][jj]);
                }
                *(uint2*)&proj_bf[(size_t)n * DH + tc * 4]      = p0.u;
                *(uint2*)&proj_bf[(size_t)n * DH + 64 + tc * 4] = p1.u;
            }
#pragma unroll
            for (int ci = 0; ci < 2; ++ci) {
                float ps = 0.f;
#pragma unroll
                for (int jj = 0; jj < 4; ++jj)
                    ps = fmaf(acc[ni][ci][ii][jj], asv[ci][jj], ps);
                ps += __shfl_xor(ps, 1);
                ps += __shfl_xor(ps, 2);
                ps += __shfl_xor(ps, 4);
                if (ok && (tc & 7) == 0) {
                    int h = ci * 2 + (tc >> 3);
                    s_src[n * 4 + h] = ps;
                }
            }
        }
}

// ---- edge prep: ONE streaming pass over edges.
// Computes edge score GEMM + full per-edge weights w = exp(s_src + s_edge),
// takes per-dst rank from the histogram atomic (which we need anyway), and
// writes ONE COALESCED 16B record per edge: {src, w01, w23, (dst<<15)|rank}.
__global__ __launch_bounds__(256)
void edgeprep_kernel(const float* __restrict__ ef, const int* __restrict__ eidx,
                     const float* __restrict__ wefold,
                     const float* __restrict__ s_src,
                     int* __restrict__ cnt, uint4* __restrict__ rec_e, int E) {
    __shared__ float wf[128];
    const int t = threadIdx.x;
    if (t < 128) wf[t] = wefold[t];
    __syncthreads();

    const int e = blockIdx.x * 256 + t;
    if (e >= E) return;
    int2 sd = ((const int2*)eidx)[e];
    int s_i = sd.x, d_i = sd.y;
    float es0 = 0.f, es1 = 0.f, es2 = 0.f, es3 = 0.f;
#pragma unroll
    for (int f4 = 0; f4 < 8; ++f4) {
        float4 v = *(const float4*)&ef[(size_t)e * F_E + f4 * 4];
        float vv[4] = {v.x, v.y, v.z, v.w};
#pragma unroll
        for (int q = 0; q < 4; ++q) {
            float4 wv = *(const float4*)&wf[(f4 * 4 + q) * 4];
            es0 = fmaf(vv[q], wv.x, es0);
            es1 = fmaf(vv[q], wv.y, es1);
            es2 = fmaf(vv[q], wv.z, es2);
            es3 = fmaf(vv[q], wv.w, es3);
        }
    }
    float4 a = *(const float4*)&s_src[s_i * 4];   // random 16B, L2-resident (1.6MB)
    // no segment-max shift, no s_dst: |logit| small; softmax ratio unchanged
    float w0 = __expf(a.x + es0), w1 = __expf(a.y + es1);
    float w2 = __expf(a.z + es2), w3 = __expf(a.w + es3);
    unsigned int u0 = __half_as_ushort(__float2half_rn(w0));
    unsigned int u1 = __half_as_ushort(__float2half_rn(w1));
    unsigned int u2 = __half_as_ushort(__float2half_rn(w2));
    unsigned int u3 = __half_as_ushort(__float2half_rn(w3));
    int r = atomicAdd(&cnt[d_i], 1);              // rank within dst segment
    uint4 R;
    R.x = (unsigned int)s_i;
    R.y = u0 | (u1 << 16);
    R.z = u2 | (u3 << 16);
    R.w = ((unsigned int)d_i << 15) | (unsigned int)r;  // d<2^17, rank<2^15
    rec_e[e] = R;                                 // coalesced 16B store
}

// ---- scan step 1: per-block exclusive scan + block sums
__global__ __launch_bounds__(256)
void scan1_kernel(const int* __restrict__ cnt, int* __restrict__ cursor,
                  int* __restrict__ bsum, int N) {
    __shared__ int s[256];
    const int t = threadIdx.x;
    int i = blockIdx.x * 256 + t;
    int v = (i < N) ? cnt[i] : 0;
    s[t] = v;
    __syncthreads();
#pragma unroll
    for (int d = 1; d < 256; d <<= 1) {
        int x = (t >= d) ? s[t - d] : 0;
        __syncthreads();
        s[t] += x;
        __syncthreads();
    }
    if (i < N) cursor[i] = s[t] - v;
    if (t == 255) bsum[blockIdx.x] = s[255];
}

// ---- scan step 2: exclusive scan of block sums (nb <= 512)
__global__ __launch_bounds__(512)
void scan2_kernel(int* __restrict__ bsum, int nb) {
    __shared__ int s[512];
    const int t = threadIdx.x;
    int v = (t < nb) ? bsum[t] : 0;
    s[t] = v;
    __syncthreads();
#pragma unroll
    for (int d = 1; d < 512; d <<= 1) {
        int x = (t >= d) ? s[t - d] : 0;
        __syncthreads();
        s[t] += x;
        __syncthreads();
    }
    if (t < nb) bsum[t] = s[t] - v;
}

// ---- scatter-lite: permute edge-order records into CSR order.
// pos = cursor[d] + bsum[d>>8] + rank  (scan3 folded in; bsum is L2-hot 1.5KB)
__global__ __launch_bounds__(256)
void scatter_kernel(const uint4* __restrict__ rec_e,
                    const int* __restrict__ cursor,
                    const int* __restrict__ bsum,
                    uint4* __restrict__ rec, int E) {
    const int e = blockIdx.x * 256 + threadIdx.x;
    if (e >= E) return;
    uint4 R = rec_e[e];
    int d = (int)(R.w >> 15);
    int r = (int)(R.w & 32767u);
    int pos = cursor[d] + bsum[d >> 8] + r;
    rec[pos] = R;
}

// ---- gather: one wave per dst node. Lane split: lanes 0-31 handle even
// edges of each batch, lanes 32-63 odd edges; each lane reads uint2 (8B) of
// the proj row, so ONE instruction fetches TWO edges' rows (512B/wave).
// Batch = 8 edges, software-pipelined (8 rec + 4 proj loads in flight).
// Loop bounds wave-uniform (readfirstlane). Tail branchless: rec has 128B
// slack; pad slots get src=0 / weight=0. Cross-half reduce via shfl_xor(32).
__global__ __launch_bounds__(256)
void gather_kernel(const int* __restrict__ cursor, const int* __restrict__ bsum,
                   const uint4* __restrict__ rec,
                   const unsigned int* __restrict__ proj_bf,
                   unsigned int* __restrict__ numer_bf, int N, int E) {
    const int t    = threadIdx.x;
    const int lane = t & 63;
    const int n    = blockIdx.x * 4 + (t >> 6);
    if (n >= N) return;

    int start = cursor[n] + bsum[n >> 8];
    int end   = (n == N - 1) ? E : (cursor[n + 1] + bsum[(n + 1) >> 8]);
    start = __builtin_amdgcn_readfirstlane(start);
    end   = __builtin_amdgcn_readfirstlane(end);

    const int hf  = lane >> 5;      // 0: even edges, 1: odd edges
    const int col = lane & 31;      // uint2 index pair within the 256B row
    const int h   = col >> 3;       // head for bf16 cols 4*col..4*col+3

    float4 acc = make_float4(0.f, 0.f, 0.f, 0.f);
    float dsum = 0.f;

    int i   = start;
    int rem = end - start;
    int c0  = rem < 8 ? rem : 8;
    uint4 ra[8];
#pragma unroll
    for (int q = 0; q < 8; ++q) ra[q] = rec[i + q];      // slack-padded buffer

    while (c0 > 0) {
        const int i1   = i + c0;
        const int rem1 = rem - c0;
        const int c1   = rem1 < 8 ? rem1 : 8;
        uint4 rb[8];
#pragma unroll
        for (int q = 0; q < 8; ++q) rb[q] = rec[i1 + q]; // prefetch next batch
        uint2 pv[4];
        unsigned int wp[4];
#pragma unroll
        for (int j = 0; j < 4; ++j) {
            bool v = (2 * j + hf) < c0;
            unsigned int sx = hf ? ra[2 * j + 1].x : ra[2 * j].x;
            unsigned int py = hf ? ra[2 * j + 1].y : ra[2 * j].y;
            unsigned int pz = hf ? ra[2 * j + 1].z : ra[2 * j].z;
            sx = v ? sx : 0u;                            // sanitize pad src
            unsigned int pk = (h < 2) ? py : pz;
            wp[j] = v ? pk : 0u;                         // pad weight = 0.0
            pv[j] = *(const uint2*)&proj_bf[(size_t)sx * 64 + col * 2];
        }
#pragma unroll
        for (int j = 0; j < 4; ++j) {
            unsigned short uw = (h & 1) ? (unsigned short)(wp[j] >> 16)
                                        : (unsigned short)(wp[j] & 0xffffu);
            float w = __half2float(__ushort_as_half(uw));
            dsum += w;
            acc.x = fmaf(w, __uint_as_float(pv[j].x << 16), acc.x);
            acc.y = fmaf(w, __uint_as_float(pv[j].x & 0xffff0000u), acc.y);
            acc.z = fmaf(w, __uint_as_float(pv[j].y << 16), acc.z);
            acc.w = fmaf(w, __uint_as_float(pv[j].y & 0xffff0000u), acc.w);
        }
#pragma unroll
        for (int q = 0; q < 8; ++q) ra[q] = rb[q];
        i = i1; rem = rem1; c0 = c1;
    }

    // combine even-edge (lanes 0-31) and odd-edge (lanes 32-63) partial sums
    dsum  += __shfl_xor(dsum, 32);
    acc.x += __shfl_xor(acc.x, 32);
    acc.y += __shfl_xor(acc.y, 32);
    acc.z += __shfl_xor(acc.z, 32);
    acc.w += __shfl_xor(acc.w, 32);

    if (hf == 0) {
        float r = 1.f / (dsum + 1e-8f);
        uint2 p;
        p.x = (unsigned int)f2bf(acc.x * r) | ((unsigned int)f2bf(acc.y * r) << 16);
        p.y = (unsigned int)f2bf(acc.z * r) | ((unsigned int)f2bf(acc.w * r) << 16);
        *(uint2*)&numer_bf[(size_t)n * 64 + col * 2] = p;  // 256B/wave contiguous
    }
}

// ---- epilogue: out = gelu(agg @ W_out + b_out); agg (bf16) already normalized
__global__ __launch_bounds__(256, 2)
void out_kernel(const unsigned int* __restrict__ numer_bf,
                const float* __restrict__ Wout, const float* __restrict__ bout,
                float* __restrict__ out, int N) {
    __shared__ float wsh[128 * 32];
    __shared__ float bsh[32];
    const int t = threadIdx.x;
    for (int i = t; i < 4096; i += 256) wsh[i] = Wout[i];
    if (t < 32) bsh[t] = bout[t];
    __syncthreads();

    int n = blockIdx.x * 256 + t;
    if (n >= N) return;

    float acc[32];
#pragma unroll
    for (int j = 0; j < 32; ++j) acc[j] = 0.f;

    for (int kg = 0; kg < 16; ++kg) {
        uint4 v = *(const uint4*)&numer_bf[(size_t)n * 64 + kg * 4];
        unsigned int vv[4] = {v.x, v.y, v.z, v.w};
#pragma unroll
        for (int q = 0; q < 4; ++q) {
            int k = kg * 8 + q * 2;
            float a0 = __uint_as_float(vv[q] << 16);
            float a1 = __uint_as_float(vv[q] & 0xffff0000u);
#pragma unroll
            for (int j = 0; j < 32; j += 4) {
                float4 w0 = *(const float4*)&wsh[k * 32 + j];
                float4 w1 = *(const float4*)&wsh[(k + 1) * 32 + j];
                acc[j + 0] = fmaf(a0, w0.x, fmaf(a1, w1.x, acc[j + 0]));
                acc[j + 1] = fmaf(a0, w0.y, fmaf(a1, w1.y, acc[j + 1]));
                acc[j + 2] = fmaf(a0, w0.z, fmaf(a1, w1.z, acc[j + 2]));
                acc[j + 3] = fmaf(a0, w0.w, fmaf(a1, w1.w, acc[j + 3]));
            }
        }
    }
#pragma unroll
    for (int j = 0; j < 32; ++j) {
        float z = acc[j] + bsh[j];
        acc[j] = 0.5f * z * (1.f + erff(z * 0.70710678118654752f));
    }
#pragma unroll
    for (int j = 0; j < 32; j += 4)
        *(float4*)&out[(size_t)n * 32 + j] = make_float4(acc[j], acc[j+1], acc[j+2], acc[j+3]);
}

extern "C" void kernel_launch(void* const* d_in, const int* in_sizes, int n_in,
                              void* d_out, int out_size, void* d_ws, size_t ws_size,
                              hipStream_t stream) {
    const float* x    = (const float*)d_in[0];
    const int*   eidx = (const int*)d_in[1];
    const float* ef   = (const float*)d_in[2];
    const float* Wn   = (const float*)d_in[3];
    const float* We   = (const float*)d_in[4];
    const float* attn = (const float*)d_in[5];
    const float* Wout = (const float*)d_in[6];
    const float* bout = (const float*)d_in[7];
    float* out = (float*)d_out;

    const int N = in_sizes[0] / F_IN;
    const int E = in_sizes[1] / 2;
    const int NB = (N + 255) / 256;          // scan blocks; must be <= 512

    char* ws = (char*)d_ws;
    size_t off = 0;
    auto alloc = [&](size_t bytes) {
        void* p = ws + off;
        off = (off + bytes + 255) & ~(size_t)255;
        return p;
    };
    int*   cnt     = (int*)  alloc((size_t)N * 4);           // zeroed
    size_t zero_bytes = off;                                 // 400 KB
    int*   cursor  = (int*)  alloc((size_t)N * 4);
    int*   bsum    = (int*)  alloc(512 * 4);
    float* wefold  = (float*)alloc(512);
    float* s_src   = (float*)alloc((size_t)N * 4 * 4);
    unsigned short* proj_bf = (unsigned short*)alloc((size_t)N * DH * 2);  // 25.6 MB
    size_t numer_bytes = (size_t)N * 64 * 4;                 // 25.6 MB
    size_t rece_bytes  = (size_t)E * 16;                     // 25.6 MB
    unsigned int* numer_bf = (unsigned int*)alloc(numer_bytes > rece_bytes ?
                                                  numer_bytes : rece_bytes);
    uint4* rec_e   = (uint4*)numer_bf;       // alias: rec_e dead before gather writes
    uint4* rec     = (uint4*)alloc((size_t)E * 16 + 128);    // +128B slack for prefetch

    hipMemsetAsync(d_ws, 0, zero_bytes, stream);
    hipLaunchKernelGGL(prep_kernel, dim3(1), dim3(128), 0, stream, We, attn, wefold);
    hipLaunchKernelGGL(node_proj_kernel, dim3((N + 127) / 128), dim3(256), 0, stream,
                       x, Wn, attn, proj_bf, s_src, N);
    hipLaunchKernelGGL(edgeprep_kernel, dim3((E + 255) / 256), dim3(256), 0, stream,
                       ef, eidx, wefold, s_src, cnt, rec_e, E);
    hipLaunchKernelGGL(scan1_kernel, dim3(NB), dim3(256), 0, stream, cnt, cursor, bsum, N);
    hipLaunchKernelGGL(scan2_kernel, dim3(1), dim3(512), 0, stream, bsum, NB);
    hipLaunchKernelGGL(scatter_kernel, dim3((E + 255) / 256), dim3(256), 0, stream,
                       rec_e, cursor, bsum, rec, E);
    hipLaunchKernelGGL(gather_kernel, dim3((N + 3) / 4), dim3(256), 0, stream,
                       cursor, bsum, rec, (const unsigned int*)proj_bf, numer_bf, N, E);
    hipLaunchKernelGGL(out_kernel, dim3((N + 255) / 256), dim3(256), 0, stream,
                       numer_bf, Wout, bout, out, N);
}

// Round 5
// 522.604 us; speedup vs baseline: 2.0611x; 2.0611x over previous
//
#include <hip/hip_runtime.h>
#include <hip/hip_bf16.h>
#include <hip/hip_fp16.h>

#define F_IN 128
#define F_E  32
#define DH   128   // D*H
#define HD   32    // D

__device__ __forceinline__ unsigned short f2bf(float f) {
    unsigned int x = __float_as_uint(f);
    unsigned int r = (x + 0x7fffu + ((x >> 16) & 1u)) >> 16;   // RNE
    return (unsigned short)r;
}

// ---- prep: We_fold[f][h] = sum_d W_edge[f][h*32+d] * attn[h][64+d]  (32x4)
__global__ void prep_kernel(const float* __restrict__ W_edge,
                            const float* __restrict__ attn,
                            float* __restrict__ wefold) {
    int t = threadIdx.x;            // 128 threads
    int f = t >> 2, h = t & 3;
    float s = 0.f;
#pragma unroll
    for (int d = 0; d < 32; ++d)
        s += W_edge[f * DH + h * HD + d] * attn[h * 96 + 64 + d];
    wefold[f * 4 + h] = s;
}

// ---- node projection GEMM (128x128 tile, 8x8 micro-tile) + per-head src scores
// s_dst is dropped: softmax ratio is invariant to the per-dst factor exp(s_dst).
__global__ __launch_bounds__(256, 4)
void node_proj_kernel(const float* __restrict__ x, const float* __restrict__ Wn,
                      const float* __restrict__ attn,
                      unsigned short* __restrict__ proj_bf,
                      float* __restrict__ s_src, int N) {
    __shared__ float xsT[32 * 132];
    __shared__ float ws[32 * 132];
    const int t  = threadIdx.x;
    const int n0 = blockIdx.x * 128;
    const int tc = t & 15, tn = t >> 4;
    const float4* x4  = (const float4*)x;
    const float4* Wn4 = (const float4*)Wn;

    float acc[2][2][4][4];
#pragma unroll
    for (int a = 0; a < 2; ++a)
#pragma unroll
        for (int b = 0; b < 2; ++b)
#pragma unroll
            for (int i = 0; i < 4; ++i)
#pragma unroll
                for (int j = 0; j < 4; ++j) acc[a][b][i][j] = 0.f;

    for (int ch = 0; ch < 4; ++ch) {
        __syncthreads();
        // stage x chunk transposed: xsT[kk][n]
#pragma unroll
        for (int j = 0; j < 4; ++j) {
            int idx = t + j * 256;          // 0..1023
            int n  = idx >> 3;              // 0..127
            int kq = idx & 7;               // 0..7 (float4 group)
            float4 v = make_float4(0.f, 0.f, 0.f, 0.f);
            if (n0 + n < N) v = x4[(size_t)(n0 + n) * 32 + ch * 8 + kq];
            int kk = kq * 4;
            xsT[(kk + 0) * 132 + n] = v.x;
            xsT[(kk + 1) * 132 + n] = v.y;
            xsT[(kk + 2) * 132 + n] = v.z;
            xsT[(kk + 3) * 132 + n] = v.w;
        }
        // stage W chunk row-major: ws[kk][c]
#pragma unroll
        for (int j = 0; j < 4; ++j) {
            int idx = t + j * 256;
            int kk = idx >> 5, cq = idx & 31;
            float4 v = Wn4[(size_t)(ch * 32 + kk) * 32 + cq];
            *(float4*)&ws[kk * 132 + cq * 4] = v;
        }
        __syncthreads();
#pragma unroll 4
        for (int kk = 0; kk < 32; ++kk) {
            float4 a0 = *(const float4*)&xsT[kk * 132 + tn * 4];
            float4 a1 = *(const float4*)&xsT[kk * 132 + 64 + tn * 4];
            float4 b0 = *(const float4*)&ws[kk * 132 + tc * 4];
            float4 b1 = *(const float4*)&ws[kk * 132 + 64 + tc * 4];
            float av[2][4] = {{a0.x, a0.y, a0.z, a0.w}, {a1.x, a1.y, a1.z, a1.w}};
            float bv[2][4] = {{b0.x, b0.y, b0.z, b0.w}, {b1.x, b1.y, b1.z, b1.w}};
#pragma unroll
            for (int ni = 0; ni < 2; ++ni)
#pragma unroll
                for (int ci = 0; ci < 2; ++ci)
#pragma unroll
                    for (int ii = 0; ii < 4; ++ii)
#pragma unroll
                        for (int jj = 0; jj < 4; ++jj)
                            acc[ni][ci][ii][jj] =
                                fmaf(av[ni][ii], bv[ci][jj], acc[ni][ci][ii][jj]);
        }
    }

    // epilogue: attention (src) vectors for this thread's 8 cols
    float asv[2][4];
#pragma unroll
    for (int ci = 0; ci < 2; ++ci)
#pragma unroll
        for (int jj = 0; jj < 4; ++jj) {
            int c = ci * 64 + tc * 4 + jj;
            int h = c >> 5, d = c & 31;
            asv[ci][jj] = attn[h * 96 + d];
        }

#pragma unroll
    for (int ni = 0; ni < 2; ++ni)
#pragma unroll
        for (int ii = 0; ii < 4; ++ii) {
            int n = n0 + ni * 64 + tn * 4 + ii;
            bool ok = (n < N);
            if (ok) {
                union { unsigned short h[4]; uint2 u; } p0, p1;
#pragma unroll
                for (int jj = 0; jj < 4; ++jj) {
                    p0.h[jj] = f2bf(acc[ni][0][ii][jj]);
                    p1.h[jj] = f2bf(acc[ni][1][ii][jj]);
                }
                *(uint2*)&proj_bf[(size_t)n * DH + tc * 4]      = p0.u;
                *(uint2*)&proj_bf[(size_t)n * DH + 64 + tc * 4] = p1.u;
            }
#pragma unroll
            for (int ci = 0; ci < 2; ++ci) {
                float ps = 0.f;
#pragma unroll
                for (int jj = 0; jj < 4; ++jj)
                    ps = fmaf(acc[ni][ci][ii][jj], asv[ci][jj], ps);
                ps += __shfl_xor(ps, 1);
                ps += __shfl_xor(ps, 2);
                ps += __shfl_xor(ps, 4);
                if (ok && (tc & 7) == 0) {
                    int h = ci * 2 + (tc >> 3);
                    s_src[n * 4 + h] = ps;
                }
            }
        }
}

// ---- edge prep: ONE streaming pass over edges.
// Computes edge score GEMM + full per-edge weights w = exp(s_src + s_edge),
// takes per-dst rank from the histogram atomic (which we need anyway), and
// writes ONE COALESCED 16B record per edge: {src, w01, w23, (dst<<15)|rank}.
__global__ __launch_bounds__(256)
void edgeprep_kernel(const float* __restrict__ ef, const int* __restrict__ eidx,
                     const float* __restrict__ wefold,
                     const float* __restrict__ s_src,
                     int* __restrict__ cnt, uint4* __restrict__ rec_e, int E) {
    __shared__ float wf[128];
    const int t = threadIdx.x;
    if (t < 128) wf[t] = wefold[t];
    __syncthreads();

    const int e = blockIdx.x * 256 + t;
    if (e >= E) return;
    int2 sd = ((const int2*)eidx)[e];
    int s_i = sd.x, d_i = sd.y;
    float es0 = 0.f, es1 = 0.f, es2 = 0.f, es3 = 0.f;
#pragma unroll
    for (int f4 = 0; f4 < 8; ++f4) {
        float4 v = *(const float4*)&ef[(size_t)e * F_E + f4 * 4];
        float vv[4] = {v.x, v.y, v.z, v.w};
#pragma unroll
        for (int q = 0; q < 4; ++q) {
            float4 wv = *(const float4*)&wf[(f4 * 4 + q) * 4];
            es0 = fmaf(vv[q], wv.x, es0);
            es1 = fmaf(vv[q], wv.y, es1);
            es2 = fmaf(vv[q], wv.z, es2);
            es3 = fmaf(vv[q], wv.w, es3);
        }
    }
    float4 a = *(const float4*)&s_src[s_i * 4];   // random 16B, L2-resident (1.6MB)
    // no segment-max shift, no s_dst: |logit| small; softmax ratio unchanged
    float w0 = __expf(a.x + es0), w1 = __expf(a.y + es1);
    float w2 = __expf(a.z + es2), w3 = __expf(a.w + es3);
    unsigned int u0 = __half_as_ushort(__float2half_rn(w0));
    unsigned int u1 = __half_as_ushort(__float2half_rn(w1));
    unsigned int u2 = __half_as_ushort(__float2half_rn(w2));
    unsigned int u3 = __half_as_ushort(__float2half_rn(w3));
    int r = atomicAdd(&cnt[d_i], 1);              // rank within dst segment
    uint4 R;
    R.x = (unsigned int)s_i;
    R.y = u0 | (u1 << 16);
    R.z = u2 | (u3 << 16);
    R.w = ((unsigned int)d_i << 15) | (unsigned int)r;  // d<2^17, rank<2^15
    rec_e[e] = R;                                 // coalesced 16B store
}

// ---- scan step 1: per-block exclusive scan + block sums
__global__ __launch_bounds__(256)
void scan1_kernel(const int* __restrict__ cnt, int* __restrict__ cursor,
                  int* __restrict__ bsum, int N) {
    __shared__ int s[256];
    const int t = threadIdx.x;
    int i = blockIdx.x * 256 + t;
    int v = (i < N) ? cnt[i] : 0;
    s[t] = v;
    __syncthreads();
#pragma unroll
    for (int d = 1; d < 256; d <<= 1) {
        int x = (t >= d) ? s[t - d] : 0;
        __syncthreads();
        s[t] += x;
        __syncthreads();
    }
    if (i < N) cursor[i] = s[t] - v;
    if (t == 255) bsum[blockIdx.x] = s[255];
}

// ---- scan step 2: exclusive scan of block sums (nb <= 512)
__global__ __launch_bounds__(512)
void scan2_kernel(int* __restrict__ bsum, int nb) {
    __shared__ int s[512];
    const int t = threadIdx.x;
    int v = (t < nb) ? bsum[t] : 0;
    s[t] = v;
    __syncthreads();
#pragma unroll
    for (int d = 1; d < 512; d <<= 1) {
        int x = (t >= d) ? s[t - d] : 0;
        __syncthreads();
        s[t] += x;
        __syncthreads();
    }
    if (t < nb) bsum[t] = s[t] - v;
}

// ---- scatter-lite: permute edge-order records into CSR order.
// pos = cursor[d] + bsum[d>>8] + rank  (scan3 folded in; bsum is L2-hot 1.5KB)
__global__ __launch_bounds__(256)
void scatter_kernel(const uint4* __restrict__ rec_e,
                    const int* __restrict__ cursor,
                    const int* __restrict__ bsum,
                    uint4* __restrict__ rec, int E) {
    const int e = blockIdx.x * 256 + threadIdx.x;
    if (e >= E) return;
    uint4 R = rec_e[e];
    int d = (int)(R.w >> 15);
    int r = (int)(R.w & 32767u);
    int pos = cursor[d] + bsum[d >> 8] + r;
    rec[pos] = R;
}

// ---- gather: one wave per dst node. Lanes 0-31 handle even edges of each
// batch, lanes 32-63 odd edges; each lane reads uint2 (8B) of the proj row,
// so ONE instruction fetches TWO edges' rows (512B/wave). Batch = 8 edges,
// software-pipelined. ALL pipeline state in NAMED registers -- no local
// arrays, so no runtime-index canonicalization -> no scratch (round-4 bug:
// `hf ? ra[2j+1] : ra[2j]` became ra[2j+hf] -> localMem, 2.8GB spill traffic).
// Loop bounds wave-uniform (readfirstlane). Tail branchless: rec has 128B
// slack; pad slots get src=0 / weight=0. Cross-half reduce via shfl_xor(32).
__global__ __launch_bounds__(256)
void gather_kernel(const int* __restrict__ cursor, const int* __restrict__ bsum,
                   const uint4* __restrict__ rec,
                   const unsigned int* __restrict__ proj_bf,
                   unsigned int* __restrict__ numer_bf, int N, int E) {
    const int t    = threadIdx.x;
    const int lane = t & 63;
    const int n    = blockIdx.x * 4 + (t >> 6);
    if (n >= N) return;

    int start = cursor[n] + bsum[n >> 8];
    int end   = (n == N - 1) ? E : (cursor[n + 1] + bsum[(n + 1) >> 8]);
    start = __builtin_amdgcn_readfirstlane(start);
    end   = __builtin_amdgcn_readfirstlane(end);

    const int  hf  = lane >> 5;      // 0: even edges, 1: odd edges
    const int  col = lane & 31;      // uint2 pair index within the 256B row
    const int  h   = col >> 3;       // head for bf16 cols 4*col..4*col+3
    const bool hiw = (h & 1) != 0;   // which half of packed weight word
    const bool low = (h < 2);        // which weight word (y or z)

    float4 acc = make_float4(0.f, 0.f, 0.f, 0.f);
    float dsum = 0.f;

    // select this lane's (src, packed-weight) for edge-pair j from two recs
    auto SEL = [&](uint4 qa, uint4 qb, int j, int cc,
                   unsigned int& sx, unsigned int& wp) {
        unsigned int s  = hf ? qb.x : qa.x;
        unsigned int py = hf ? qb.y : qa.y;
        unsigned int pz = hf ? qb.z : qa.z;
        bool v = (2 * j + hf) < cc;
        sx = v ? s : 0u;                       // sanitize pad src
        unsigned int pk = low ? py : pz;
        wp = v ? pk : 0u;                      // pad weight = 0.0
    };
    auto FMA = [&](unsigned int wp, uint2 pv) {
        unsigned short uw = hiw ? (unsigned short)(wp >> 16)
                                : (unsigned short)(wp & 0xffffu);
        float w = __half2float(__ushort_as_half(uw));
        dsum += w;
        acc.x = fmaf(w, __uint_as_float(pv.x << 16), acc.x);
        acc.y = fmaf(w, __uint_as_float(pv.x & 0xffff0000u), acc.y);
        acc.z = fmaf(w, __uint_as_float(pv.y << 16), acc.z);
        acc.w = fmaf(w, __uint_as_float(pv.y & 0xffff0000u), acc.w);
    };

    int i   = start;
    int rem = end - start;
    int c0  = rem < 8 ? rem : 8;

    unsigned int sx0, sx1, sx2, sx3, wp0, wp1, wp2, wp3;
    {   // prologue: load + select batch 0 (slack-padded buffer)
        uint4 q0 = rec[i + 0], q1 = rec[i + 1], q2 = rec[i + 2], q3 = rec[i + 3];
        uint4 q4 = rec[i + 4], q5 = rec[i + 5], q6 = rec[i + 6], q7 = rec[i + 7];
        SEL(q0, q1, 0, c0, sx0, wp0);
        SEL(q2, q3, 1, c0, sx1, wp1);
        SEL(q4, q5, 2, c0, sx2, wp2);
        SEL(q6, q7, 3, c0, sx3, wp3);
    }

    while (c0 > 0) {
        const int i1   = i + c0;
        const int rem1 = rem - c0;
        const int c1   = rem1 < 8 ? rem1 : 8;
        // prefetch next batch's recs (wave-uniform addresses)
        uint4 q0 = rec[i1 + 0], q1 = rec[i1 + 1], q2 = rec[i1 + 2], q3 = rec[i1 + 3];
        uint4 q4 = rec[i1 + 4], q5 = rec[i1 + 5], q6 = rec[i1 + 6], q7 = rec[i1 + 7];
        // dual-row proj loads for current batch (independent of prefetch)
        uint2 pv0 = *(const uint2*)&proj_bf[(size_t)sx0 * 64 + col * 2];
        uint2 pv1 = *(const uint2*)&proj_bf[(size_t)sx1 * 64 + col * 2];
        uint2 pv2 = *(const uint2*)&proj_bf[(size_t)sx2 * 64 + col * 2];
        uint2 pv3 = *(const uint2*)&proj_bf[(size_t)sx3 * 64 + col * 2];
        FMA(wp0, pv0);
        FMA(wp1, pv1);
        FMA(wp2, pv2);
        FMA(wp3, pv3);
        // select next batch into named state
        SEL(q0, q1, 0, c1, sx0, wp0);
        SEL(q2, q3, 1, c1, sx1, wp1);
        SEL(q4, q5, 2, c1, sx2, wp2);
        SEL(q6, q7, 3, c1, sx3, wp3);
        i = i1; rem = rem1; c0 = c1;
    }

    // combine even-edge (lanes 0-31) and odd-edge (lanes 32-63) partial sums
    dsum  += __shfl_xor(dsum, 32);
    acc.x += __shfl_xor(acc.x, 32);
    acc.y += __shfl_xor(acc.y, 32);
    acc.z += __shfl_xor(acc.z, 32);
    acc.w += __shfl_xor(acc.w, 32);

    if (hf == 0) {
        float r = 1.f / (dsum + 1e-8f);
        uint2 p;
        p.x = (unsigned int)f2bf(acc.x * r) | ((unsigned int)f2bf(acc.y * r) << 16);
        p.y = (unsigned int)f2bf(acc.z * r) | ((unsigned int)f2bf(acc.w * r) << 16);
        *(uint2*)&numer_bf[(size_t)n * 64 + col * 2] = p;  // 256B/wave contiguous
    }
}

// ---- epilogue: out = gelu(agg @ W_out + b_out); agg (bf16) already normalized
__global__ __launch_bounds__(256, 2)
void out_kernel(const unsigned int* __restrict__ numer_bf,
                const float* __restrict__ Wout, const float* __restrict__ bout,
                float* __restrict__ out, int N) {
    __shared__ float wsh[128 * 32];
    __shared__ float bsh[32];
    const int t = threadIdx.x;
    for (int i = t; i < 4096; i += 256) wsh[i] = Wout[i];
    if (t < 32) bsh[t] = bout[t];
    __syncthreads();

    int n = blockIdx.x * 256 + t;
    if (n >= N) return;

    float acc[32];
#pragma unroll
    for (int j = 0; j < 32; ++j) acc[j] = 0.f;

    for (int kg = 0; kg < 16; ++kg) {
        uint4 v = *(const uint4*)&numer_bf[(size_t)n * 64 + kg * 4];
        unsigned int vv[4] = {v.x, v.y, v.z, v.w};
#pragma unroll
        for (int q = 0; q < 4; ++q) {
            int k = kg * 8 + q * 2;
            float a0 = __uint_as_float(vv[q] << 16);
            float a1 = __uint_as_float(vv[q] & 0xffff0000u);
#pragma unroll
            for (int j = 0; j < 32; j += 4) {
                float4 w0 = *(const float4*)&wsh[k * 32 + j];
                float4 w1 = *(const float4*)&wsh[(k + 1) * 32 + j];
                acc[j + 0] = fmaf(a0, w0.x, fmaf(a1, w1.x, acc[j + 0]));
                acc[j + 1] = fmaf(a0, w0.y, fmaf(a1, w1.y, acc[j + 1]));
                acc[j + 2] = fmaf(a0, w0.z, fmaf(a1, w1.z, acc[j + 2]));
                acc[j + 3] = fmaf(a0, w0.w, fmaf(a1, w1.w, acc[j + 3]));
            }
        }
    }
#pragma unroll
    for (int j = 0; j < 32; ++j) {
        float z = acc[j] + bsh[j];
        acc[j] = 0.5f * z * (1.f + erff(z * 0.70710678118654752f));
    }
#pragma unroll
    for (int j = 0; j < 32; j += 4)
        *(float4*)&out[(size_t)n * 32 + j] = make_float4(acc[j], acc[j+1], acc[j+2], acc[j+3]);
}

extern "C" void kernel_launch(void* const* d_in, const int* in_sizes, int n_in,
                              void* d_out, int out_size, void* d_ws, size_t ws_size,
                              hipStream_t stream) {
    const float* x    = (const float*)d_in[0];
    const int*   eidx = (const int*)d_in[1];
    const float* ef   = (const float*)d_in[2];
    const float* Wn   = (const float*)d_in[3];
    const float* We   = (const float*)d_in[4];
    const float* attn = (const float*)d_in[5];
    const float* Wout = (const float*)d_in[6];
    const float* bout = (const float*)d_in[7];
    float* out = (float*)d_out;

    const int N = in_sizes[0] / F_IN;
    const int E = in_sizes[1] / 2;
    const int NB = (N + 255) / 256;          // scan blocks; must be <= 512

    char* ws = (char*)d_ws;
    size_t off = 0;
    auto alloc = [&](size_t bytes) {
        void* p = ws + off;
        off = (off + bytes + 255) & ~(size_t)255;
        return p;
    };
    int*   cnt     = (int*)  alloc((size_t)N * 4);           // zeroed
    size_t zero_bytes = off;                                 // 400 KB
    int*   cursor  = (int*)  alloc((size_t)N * 4);
    int*   bsum    = (int*)  alloc(512 * 4);
    float* wefold  = (float*)alloc(512);
    float* s_src   = (float*)alloc((size_t)N * 4 * 4);
    unsigned short* proj_bf = (unsigned short*)alloc((size_t)N * DH * 2);  // 25.6 MB
    size_t numer_bytes = (size_t)N * 64 * 4;                 // 25.6 MB
    size_t rece_bytes  = (size_t)E * 16;                     // 25.6 MB
    unsigned int* numer_bf = (unsigned int*)alloc(numer_bytes > rece_bytes ?
                                                  numer_bytes : rece_bytes);
    uint4* rec_e   = (uint4*)numer_bf;       // alias: rec_e dead before gather writes
    uint4* rec     = (uint4*)alloc((size_t)E * 16 + 128);    // +128B slack for prefetch

    hipMemsetAsync(d_ws, 0, zero_bytes, stream);
    hipLaunchKernelGGL(prep_kernel, dim3(1), dim3(128), 0, stream, We, attn, wefold);
    hipLaunchKernelGGL(node_proj_kernel, dim3((N + 127) / 128), dim3(256), 0, stream,
                       x, Wn, attn, proj_bf, s_src, N);
    hipLaunchKernelGGL(edgeprep_kernel, dim3((E + 255) / 256), dim3(256), 0, stream,
                       ef, eidx, wefold, s_src, cnt, rec_e, E);
    hipLaunchKernelGGL(scan1_kernel, dim3(NB), dim3(256), 0, stream, cnt, cursor, bsum, N);
    hipLaunchKernelGGL(scan2_kernel, dim3(1), dim3(512), 0, stream, bsum, NB);
    hipLaunchKernelGGL(scatter_kernel, dim3((E + 255) / 256), dim3(256), 0, stream,
                       rec_e, cursor, bsum, rec, E);
    hipLaunchKernelGGL(gather_kernel, dim3((N + 3) / 4), dim3(256), 0, stream,
                       cursor, bsum, rec, (const unsigned int*)proj_bf, numer_bf, N, E);
    hipLaunchKernelGGL(out_kernel, dim3((N + 255) / 256), dim3(256), 0, stream,
                       numer_bf, Wout, bout, out, N);
}

// Round 6
// 512.203 us; speedup vs baseline: 2.1030x; 1.0203x over previous
//
#include <hip/hip_runtime.h>
#include <hip/hip_bf16.h>
#include <hip/hip_fp16.h>

#define F_IN 128
#define F_E  32
#define DH   128   // D*H
#define HD   32    // D

using bf16x8 = __attribute__((ext_vector_type(8))) short;
using f32x4  = __attribute__((ext_vector_type(4))) float;

__device__ __forceinline__ unsigned short f2bf(float f) {
    unsigned int x = __float_as_uint(f);
    unsigned int r = (x + 0x7fffu + ((x >> 16) & 1u)) >> 16;   // RNE
    return (unsigned short)r;
}

// ---- prep: We_fold[f][h] = sum_d W_edge[f][h*32+d] * attn[h][64+d]  (32x4)
__global__ void prep_kernel(const float* __restrict__ W_edge,
                            const float* __restrict__ attn,
                            float* __restrict__ wefold) {
    int t = threadIdx.x;            // 128 threads
    int f = t >> 2, h = t & 3;
    float s = 0.f;
#pragma unroll
    for (int d = 0; d < 32; ++d)
        s += W_edge[f * DH + h * HD + d] * attn[h * 96 + 64 + d];
    wefold[f * 4 + h] = s;
}

// ---- node projection via MFMA (bf16 in, fp32 accum) + per-head src scores.
// Tile: 128 rows x 128 cols x K=128 per 256-thread block (4 waves).
// LDS: x-tile bf16 [128][128] + W^T bf16 [col][k], both XOR-swizzled
// (byte ^= (row&7)<<4) to break the stride-256B 16-way bank conflict.
// Wave w computes rows w*32..w*32+31 (2 row-frags x 8 col-frags x 4 K-steps).
// C layout (verified m89): col = lane&15, row = (lane>>4)*4 + reg.
__global__ __launch_bounds__(256, 2)
void node_proj_kernel(const float* __restrict__ x, const float* __restrict__ Wn,
                      const float* __restrict__ attn,
                      unsigned short* __restrict__ proj_bf,
                      float* __restrict__ s_src, int N) {
    __shared__ __align__(16) unsigned char xb[32768];
    __shared__ __align__(16) unsigned char wb[32768];
    const int t    = threadIdx.x;
    const int n0   = blockIdx.x * 128;
    const int lane = t & 63;
    const int wid  = t >> 6;
    const int lg   = lane >> 4;       // lane group 0..3 (k-subrange)
    const int lm   = lane & 15;

    // ---- stage x tile (fp32 -> bf16), swizzled; 16 float4 per thread
    {
        const float4* x4 = (const float4*)x;
#pragma unroll
        for (int j = 0; j < 16; ++j) {
            int idx = t + j * 256;          // 0..4095
            int n   = idx >> 5;             // row 0..127
            int kq  = idx & 31;             // float4 index along K
            float4 v = make_float4(0.f, 0.f, 0.f, 0.f);
            if (n0 + n < N) v = x4[(size_t)(n0 + n) * 32 + kq];
            unsigned int lo = (unsigned int)f2bf(v.x) | ((unsigned int)f2bf(v.y) << 16);
            unsigned int hi = (unsigned int)f2bf(v.z) | ((unsigned int)f2bf(v.w) << 16);
            int byte = (n * 256 + kq * 8) ^ ((n & 7) << 4);
            *(uint2*)&xb[byte] = make_uint2(lo, hi);
        }
    }
    // ---- stage W^T (fp32 -> bf16): thread covers col c, 64 k's; coalesced
    // global reads (lanes span consecutive c); Wn is 64KB, L2-hot.
    {
        const int c  = t & 127;
        const int kg = t >> 7;
#pragma unroll
        for (int jb = 0; jb < 8; ++jb) {
            int k0 = kg * 64 + jb * 8;
            unsigned int p0, p1, p2, p3;
            {
                float a0 = Wn[(size_t)(k0 + 0) * 128 + c];
                float a1 = Wn[(size_t)(k0 + 1) * 128 + c];
                float a2 = Wn[(size_t)(k0 + 2) * 128 + c];
                float a3 = Wn[(size_t)(k0 + 3) * 128 + c];
                float a4 = Wn[(size_t)(k0 + 4) * 128 + c];
                float a5 = Wn[(size_t)(k0 + 5) * 128 + c];
                float a6 = Wn[(size_t)(k0 + 6) * 128 + c];
                float a7 = Wn[(size_t)(k0 + 7) * 128 + c];
                p0 = (unsigned int)f2bf(a0) | ((unsigned int)f2bf(a1) << 16);
                p1 = (unsigned int)f2bf(a2) | ((unsigned int)f2bf(a3) << 16);
                p2 = (unsigned int)f2bf(a4) | ((unsigned int)f2bf(a5) << 16);
                p3 = (unsigned int)f2bf(a6) | ((unsigned int)f2bf(a7) << 16);
            }
            int byte = (c * 256 + k0 * 2) ^ ((c & 7) << 4);
            *(uint4*)&wb[byte] = make_uint4(p0, p1, p2, p3);
        }
    }
    __syncthreads();

    // ---- MFMA main: wave computes 32 rows x 128 cols
    const int wrow = wid * 32;
    f32x4 acc[2][8];
#pragma unroll
    for (int fm = 0; fm < 2; ++fm)
#pragma unroll
        for (int fn = 0; fn < 8; ++fn)
#pragma unroll
            for (int q = 0; q < 4; ++q) acc[fm][fn][q] = 0.f;

#pragma unroll
    for (int ks = 0; ks < 4; ++ks) {
        bf16x8 bfr[8];
#pragma unroll
        for (int fn = 0; fn < 8; ++fn) {
            int col  = fn * 16 + lm;
            int byte = (col * 256 + ks * 64 + lg * 16) ^ ((col & 7) << 4);
            bfr[fn] = *(const bf16x8*)&wb[byte];
        }
#pragma unroll
        for (int fm = 0; fm < 2; ++fm) {
            int row  = wrow + fm * 16 + lm;
            int byte = (row * 256 + ks * 64 + lg * 16) ^ ((row & 7) << 4);
            bf16x8 afr = *(const bf16x8*)&xb[byte];
#pragma unroll
            for (int fn = 0; fn < 8; ++fn)
                acc[fm][fn] = __builtin_amdgcn_mfma_f32_16x16x32_bf16(
                    afr, bfr[fn], acc[fm][fn], 0, 0, 0);
        }
    }

    // ---- s_src epilogue: lanes 0-15 of each group hold 16 cols of one row;
    // head h spans frags 2h,2h+1; 16-lane shfl_xor reduce.
    float asv[8];
#pragma unroll
    for (int fn = 0; fn < 8; ++fn)
        asv[fn] = attn[(fn >> 1) * 96 + (fn & 1) * 16 + lm];
#pragma unroll
    for (int fm = 0; fm < 2; ++fm)
#pragma unroll
        for (int j = 0; j < 4; ++j) {
            int row = n0 + wrow + fm * 16 + lg * 4 + j;
#pragma unroll
            for (int h = 0; h < 4; ++h) {
                float ps = fmaf(acc[fm][2 * h][j], asv[2 * h],
                                acc[fm][2 * h + 1][j] * asv[2 * h + 1]);
                ps += __shfl_xor(ps, 1);
                ps += __shfl_xor(ps, 2);
                ps += __shfl_xor(ps, 4);
                ps += __shfl_xor(ps, 8);
                if (lm == h && row < N) s_src[row * 4 + h] = ps;
            }
        }

    // ---- proj epilogue: acc -> LDS bf16 [row][col] (reuse xb), then
    // fully-coalesced uint4 copy-out.
    __syncthreads();
#pragma unroll
    for (int fm = 0; fm < 2; ++fm)
#pragma unroll
        for (int fn = 0; fn < 8; ++fn)
#pragma unroll
            for (int j = 0; j < 4; ++j) {
                int r = wrow + fm * 16 + lg * 4 + j;
                int c = fn * 16 + lm;
                *(unsigned short*)&xb[r * 256 + c * 2] = f2bf(acc[fm][fn][j]);
            }
    __syncthreads();
#pragma unroll
    for (int j = 0; j < 8; ++j) {
        int idx = t + j * 256;              // 0..2047 (16B chunks)
        int row = idx >> 4;
        if (n0 + row < N) {
            uint4 v = *(const uint4*)&xb[idx * 16];
            *(uint4*)&proj_bf[(size_t)(n0 + row) * 128 + (idx & 15) * 8] = v;
        }
    }
}

// ---- edge prep: ONE streaming pass over edges.
// Computes edge score GEMM + full per-edge weights w = exp(s_src + s_edge),
// takes per-dst rank from the histogram atomic (which we need anyway), and
// writes ONE COALESCED 16B record per edge: {src, w01, w23, (dst<<15)|rank}.
__global__ __launch_bounds__(256)
void edgeprep_kernel(const float* __restrict__ ef, const int* __restrict__ eidx,
                     const float* __restrict__ wefold,
                     const float* __restrict__ s_src,
                     int* __restrict__ cnt, uint4* __restrict__ rec_e, int E) {
    __shared__ float wf[128];
    const int t = threadIdx.x;
    if (t < 128) wf[t] = wefold[t];
    __syncthreads();

    const int e = blockIdx.x * 256 + t;
    if (e >= E) return;
    int2 sd = ((const int2*)eidx)[e];
    int s_i = sd.x, d_i = sd.y;
    float es0 = 0.f, es1 = 0.f, es2 = 0.f, es3 = 0.f;
#pragma unroll
    for (int f4 = 0; f4 < 8; ++f4) {
        float4 v = *(const float4*)&ef[(size_t)e * F_E + f4 * 4];
        float vv[4] = {v.x, v.y, v.z, v.w};
#pragma unroll
        for (int q = 0; q < 4; ++q) {
            float4 wv = *(const float4*)&wf[(f4 * 4 + q) * 4];
            es0 = fmaf(vv[q], wv.x, es0);
            es1 = fmaf(vv[q], wv.y, es1);
            es2 = fmaf(vv[q], wv.z, es2);
            es3 = fmaf(vv[q], wv.w, es3);
        }
    }
    float4 a = *(const float4*)&s_src[s_i * 4];   // random 16B, L2-resident (1.6MB)
    // no segment-max shift, no s_dst: |logit| small; softmax ratio unchanged
    float w0 = __expf(a.x + es0), w1 = __expf(a.y + es1);
    float w2 = __expf(a.z + es2), w3 = __expf(a.w + es3);
    unsigned int u0 = __half_as_ushort(__float2half_rn(w0));
    unsigned int u1 = __half_as_ushort(__float2half_rn(w1));
    unsigned int u2 = __half_as_ushort(__float2half_rn(w2));
    unsigned int u3 = __half_as_ushort(__float2half_rn(w3));
    int r = atomicAdd(&cnt[d_i], 1);              // rank within dst segment
    uint4 R;
    R.x = (unsigned int)s_i;
    R.y = u0 | (u1 << 16);
    R.z = u2 | (u3 << 16);
    R.w = ((unsigned int)d_i << 15) | (unsigned int)r;  // d<2^17, rank<2^15
    rec_e[e] = R;                                 // coalesced 16B store
}

// ---- scan step 1: per-block exclusive scan + block sums
__global__ __launch_bounds__(256)
void scan1_kernel(const int* __restrict__ cnt, int* __restrict__ cursor,
                  int* __restrict__ bsum, int N) {
    __shared__ int s[256];
    const int t = threadIdx.x;
    int i = blockIdx.x * 256 + t;
    int v = (i < N) ? cnt[i] : 0;
    s[t] = v;
    __syncthreads();
#pragma unroll
    for (int d = 1; d < 256; d <<= 1) {
        int x = (t >= d) ? s[t - d] : 0;
        __syncthreads();
        s[t] += x;
        __syncthreads();
    }
    if (i < N) cursor[i] = s[t] - v;
    if (t == 255) bsum[blockIdx.x] = s[255];
}

// ---- scan step 2: exclusive scan of block sums (nb <= 512)
__global__ __launch_bounds__(512)
void scan2_kernel(int* __restrict__ bsum, int nb) {
    __shared__ int s[512];
    const int t = threadIdx.x;
    int v = (t < nb) ? bsum[t] : 0;
    s[t] = v;
    __syncthreads();
#pragma unroll
    for (int d = 1; d < 512; d <<= 1) {
        int x = (t >= d) ? s[t - d] : 0;
        __syncthreads();
        s[t] += x;
        __syncthreads();
    }
    if (t < nb) bsum[t] = s[t] - v;
}

// ---- scatter-lite: permute edge-order records into CSR order.
// pos = cursor[d] + bsum[d>>8] + rank  (scan3 folded in; bsum is L2-hot 1.5KB)
__global__ __launch_bounds__(256)
void scatter_kernel(const uint4* __restrict__ rec_e,
                    const int* __restrict__ cursor,
                    const int* __restrict__ bsum,
                    uint4* __restrict__ rec, int E) {
    const int e = blockIdx.x * 256 + threadIdx.x;
    if (e >= E) return;
    uint4 R = rec_e[e];
    int d = (int)(R.w >> 15);
    int r = (int)(R.w & 32767u);
    int pos = cursor[d] + bsum[d >> 8] + r;
    rec[pos] = R;
}

// ---- gather: one wave per dst node. Lanes 0-31 handle even edges of each
// batch, lanes 32-63 odd edges; each lane reads uint2 (8B) of the proj row,
// so ONE instruction fetches TWO edges' rows (512B/wave). Batch = 8 edges,
// software-pipelined. ALL pipeline state in NAMED registers (rule #20).
// Loop bounds wave-uniform (readfirstlane). Tail branchless: rec has 128B
// slack; pad slots get src=0 / weight=0. Cross-half reduce via shfl_xor(32).
__global__ __launch_bounds__(256)
void gather_kernel(const int* __restrict__ cursor, const int* __restrict__ bsum,
                   const uint4* __restrict__ rec,
                   const unsigned int* __restrict__ proj_bf,
                   unsigned int* __restrict__ numer_bf, int N, int E) {
    const int t    = threadIdx.x;
    const int lane = t & 63;
    const int n    = blockIdx.x * 4 + (t >> 6);
    if (n >= N) return;

    int start = cursor[n] + bsum[n >> 8];
    int end   = (n == N - 1) ? E : (cursor[n + 1] + bsum[(n + 1) >> 8]);
    start = __builtin_amdgcn_readfirstlane(start);
    end   = __builtin_amdgcn_readfirstlane(end);

    const int  hf  = lane >> 5;      // 0: even edges, 1: odd edges
    const int  col = lane & 31;      // uint2 pair index within the 256B row
    const int  h   = col >> 3;       // head for bf16 cols 4*col..4*col+3
    const bool hiw = (h & 1) != 0;   // which half of packed weight word
    const bool low = (h < 2);        // which weight word (y or z)

    float4 acc = make_float4(0.f, 0.f, 0.f, 0.f);
    float dsum = 0.f;

    auto SEL = [&](uint4 qa, uint4 qb, int j, int cc,
                   unsigned int& sx, unsigned int& wp) {
        unsigned int s  = hf ? qb.x : qa.x;
        unsigned int py = hf ? qb.y : qa.y;
        unsigned int pz = hf ? qb.z : qa.z;
        bool v = (2 * j + hf) < cc;
        sx = v ? s : 0u;                       // sanitize pad src
        unsigned int pk = low ? py : pz;
        wp = v ? pk : 0u;                      // pad weight = 0.0
    };
    auto FMA = [&](unsigned int wp, uint2 pv) {
        unsigned short uw = hiw ? (unsigned short)(wp >> 16)
                                : (unsigned short)(wp & 0xffffu);
        float w = __half2float(__ushort_as_half(uw));
        dsum += w;
        acc.x = fmaf(w, __uint_as_float(pv.x << 16), acc.x);
        acc.y = fmaf(w, __uint_as_float(pv.x & 0xffff0000u), acc.y);
        acc.z = fmaf(w, __uint_as_float(pv.y << 16), acc.z);
        acc.w = fmaf(w, __uint_as_float(pv.y & 0xffff0000u), acc.w);
    };

    int i   = start;
    int rem = end - start;
    int c0  = rem < 8 ? rem : 8;

    unsigned int sx0, sx1, sx2, sx3, wp0, wp1, wp2, wp3;
    {   // prologue: load + select batch 0 (slack-padded buffer)
        uint4 q0 = rec[i + 0], q1 = rec[i + 1], q2 = rec[i + 2], q3 = rec[i + 3];
        uint4 q4 = rec[i + 4], q5 = rec[i + 5], q6 = rec[i + 6], q7 = rec[i + 7];
        SEL(q0, q1, 0, c0, sx0, wp0);
        SEL(q2, q3, 1, c0, sx1, wp1);
        SEL(q4, q5, 2, c0, sx2, wp2);
        SEL(q6, q7, 3, c0, sx3, wp3);
    }

    while (c0 > 0) {
        const int i1   = i + c0;
        const int rem1 = rem - c0;
        const int c1   = rem1 < 8 ? rem1 : 8;
        uint4 q0 = rec[i1 + 0], q1 = rec[i1 + 1], q2 = rec[i1 + 2], q3 = rec[i1 + 3];
        uint4 q4 = rec[i1 + 4], q5 = rec[i1 + 5], q6 = rec[i1 + 6], q7 = rec[i1 + 7];
        uint2 pv0 = *(const uint2*)&proj_bf[(size_t)sx0 * 64 + col * 2];
        uint2 pv1 = *(const uint2*)&proj_bf[(size_t)sx1 * 64 + col * 2];
        uint2 pv2 = *(const uint2*)&proj_bf[(size_t)sx2 * 64 + col * 2];
        uint2 pv3 = *(const uint2*)&proj_bf[(size_t)sx3 * 64 + col * 2];
        FMA(wp0, pv0);
        FMA(wp1, pv1);
        FMA(wp2, pv2);
        FMA(wp3, pv3);
        SEL(q0, q1, 0, c1, sx0, wp0);
        SEL(q2, q3, 1, c1, sx1, wp1);
        SEL(q4, q5, 2, c1, sx2, wp2);
        SEL(q6, q7, 3, c1, sx3, wp3);
        i = i1; rem = rem1; c0 = c1;
    }

    dsum  += __shfl_xor(dsum, 32);
    acc.x += __shfl_xor(acc.x, 32);
    acc.y += __shfl_xor(acc.y, 32);
    acc.z += __shfl_xor(acc.z, 32);
    acc.w += __shfl_xor(acc.w, 32);

    if (hf == 0) {
        float r = 1.f / (dsum + 1e-8f);
        uint2 p;
        p.x = (unsigned int)f2bf(acc.x * r) | ((unsigned int)f2bf(acc.y * r) << 16);
        p.y = (unsigned int)f2bf(acc.z * r) | ((unsigned int)f2bf(acc.w * r) << 16);
        *(uint2*)&numer_bf[(size_t)n * 64 + col * 2] = p;  // 256B/wave contiguous
    }
}

// ---- epilogue: out = gelu(agg @ W_out + b_out); agg (bf16) already normalized
__global__ __launch_bounds__(256, 2)
void out_kernel(const unsigned int* __restrict__ numer_bf,
                const float* __restrict__ Wout, const float* __restrict__ bout,
                float* __restrict__ out, int N) {
    __shared__ float wsh[128 * 32];
    __shared__ float bsh[32];
    const int t = threadIdx.x;
    for (int i = t; i < 4096; i += 256) wsh[i] = Wout[i];
    if (t < 32) bsh[t] = bout[t];
    __syncthreads();

    int n = blockIdx.x * 256 + t;
    if (n >= N) return;

    float acc[32];
#pragma unroll
    for (int j = 0; j < 32; ++j) acc[j] = 0.f;

    for (int kg = 0; kg < 16; ++kg) {
        uint4 v = *(const uint4*)&numer_bf[(size_t)n * 64 + kg * 4];
        unsigned int vv[4] = {v.x, v.y, v.z, v.w};
#pragma unroll
        for (int q = 0; q < 4; ++q) {
            int k = kg * 8 + q * 2;
            float a0 = __uint_as_float(vv[q] << 16);
            float a1 = __uint_as_float(vv[q] & 0xffff0000u);
#pragma unroll
            for (int j = 0; j < 32; j += 4) {
                float4 w0 = *(const float4*)&wsh[k * 32 + j];
                float4 w1 = *(const float4*)&wsh[(k + 1) * 32 + j];
                acc[j + 0] = fmaf(a0, w0.x, fmaf(a1, w1.x, acc[j + 0]));
                acc[j + 1] = fmaf(a0, w0.y, fmaf(a1, w1.y, acc[j + 1]));
                acc[j + 2] = fmaf(a0, w0.z, fmaf(a1, w1.z, acc[j + 2]));
                acc[j + 3] = fmaf(a0, w0.w, fmaf(a1, w1.w, acc[j + 3]));
            }
        }
    }
#pragma unroll
    for (int j = 0; j < 32; ++j) {
        float z = acc[j] + bsh[j];
        acc[j] = 0.5f * z * (1.f + erff(z * 0.70710678118654752f));
    }
#pragma unroll
    for (int j = 0; j < 32; j += 4)
        *(float4*)&out[(size_t)n * 32 + j] = make_float4(acc[j], acc[j+1], acc[j+2], acc[j+3]);
}

extern "C" void kernel_launch(void* const* d_in, const int* in_sizes, int n_in,
                              void* d_out, int out_size, void* d_ws, size_t ws_size,
                              hipStream_t stream) {
    const float* x    = (const float*)d_in[0];
    const int*   eidx = (const int*)d_in[1];
    const float* ef   = (const float*)d_in[2];
    const float* Wn   = (const float*)d_in[3];
    const float* We   = (const float*)d_in[4];
    const float* attn = (const float*)d_in[5];
    const float* Wout = (const float*)d_in[6];
    const float* bout = (const float*)d_in[7];
    float* out = (float*)d_out;

    const int N = in_sizes[0] / F_IN;
    const int E = in_sizes[1] / 2;
    const int NB = (N + 255) / 256;          // scan blocks; must be <= 512

    char* ws = (char*)d_ws;
    size_t off = 0;
    auto alloc = [&](size_t bytes) {
        void* p = ws + off;
        off = (off + bytes + 255) & ~(size_t)255;
        return p;
    };
    int*   cnt     = (int*)  alloc((size_t)N * 4);           // zeroed
    size_t zero_bytes = off;                                 // 400 KB
    int*   cursor  = (int*)  alloc((size_t)N * 4);
    int*   bsum    = (int*)  alloc(512 * 4);
    float* wefold  = (float*)alloc(512);
    float* s_src   = (float*)alloc((size_t)N * 4 * 4);
    unsigned short* proj_bf = (unsigned short*)alloc((size_t)N * DH * 2);  // 25.6 MB
    size_t numer_bytes = (size_t)N * 64 * 4;                 // 25.6 MB
    size_t rece_bytes  = (size_t)E * 16;                     // 25.6 MB
    unsigned int* numer_bf = (unsigned int*)alloc(numer_bytes > rece_bytes ?
                                                  numer_bytes : rece_bytes);
    uint4* rec_e   = (uint4*)numer_bf;       // alias: rec_e dead before gather writes
    uint4* rec     = (uint4*)alloc((size_t)E * 16 + 128);    // +128B slack for prefetch

    hipMemsetAsync(d_ws, 0, zero_bytes, stream);
    hipLaunchKernelGGL(prep_kernel, dim3(1), dim3(128), 0, stream, We, attn, wefold);
    hipLaunchKernelGGL(node_proj_kernel, dim3((N + 127) / 128), dim3(256), 0, stream,
                       x, Wn, attn, proj_bf, s_src, N);
    hipLaunchKernelGGL(edgeprep_kernel, dim3((E + 255) / 256), dim3(256), 0, stream,
                       ef, eidx, wefold, s_src, cnt, rec_e, E);
    hipLaunchKernelGGL(scan1_kernel, dim3(NB), dim3(256), 0, stream, cnt, cursor, bsum, N);
    hipLaunchKernelGGL(scan2_kernel, dim3(1), dim3(512), 0, stream, bsum, NB);
    hipLaunchKernelGGL(scatter_kernel, dim3((E + 255) / 256), dim3(256), 0, stream,
                       rec_e, cursor, bsum, rec, E);
    hipLaunchKernelGGL(gather_kernel, dim3((N + 3) / 4), dim3(256), 0, stream,
                       cursor, bsum, rec, (const unsigned int*)proj_bf, numer_bf, N, E);
    hipLaunchKernelGGL(out_kernel, dim3((N + 255) / 256), dim3(256), 0, stream,
                       numer_bf, Wout, bout, out, N);
}